// Round 1
// baseline (434.925 us; speedup 1.0000x reference)
//
#include <hip/hip_runtime.h>

// UniformBottomUpHTMM: T=64 trees, depth D=10 (N1=2047 nodes, heap layout),
// C=16 states, M=64 symbols, G=16 mixtures. One block per (tree,g).
// Bottom-up pass entirely in LDS; only ll sums hit global memory.

#define C_DIM 16
#define M_DIM 64
#define G_DIM 16
#define T_TREES 64
#define DEPTH 10
#define N1 2047

__global__ __launch_bounds__(256, 3) void htmm_kernel(
    const int* __restrict__ x,
    const int* __restrict__ inv_map,
    const float* __restrict__ lA,
    const float* __restrict__ lB,
    const float* __restrict__ lPi,
    float* __restrict__ out)
{
    const int g   = blockIdx.x & (G_DIM - 1);
    const int t   = blockIdx.x >> 4;
    const int tid = threadIdx.x;

    __shared__ float sA[C_DIM * C_DIM];   // sA[i*16+j] = softmax_i(lA[i,j,g])
    __shared__ float sB[C_DIM * M_DIM];   // sB[c*64+m] = softmax_m(lB[c,m,g])
    __shared__ float sPi[C_DIM];
    __shared__ float buf0[C_DIM * 512];   // SoA: plane stride = level node count
    __shared__ float buf1[C_DIM * 256];
    __shared__ float wsum[4];

    // ---- parameter softmaxes (one wave does all three) ----
    if (tid < C_DIM) {
        // A: softmax over axis 0 (i), column j = tid
        int j = tid;
        float v[C_DIM];
        float mx = -1e30f;
        #pragma unroll
        for (int i = 0; i < C_DIM; ++i) {
            v[i] = lA[(i * C_DIM + j) * G_DIM + g];
            mx = fmaxf(mx, v[i]);
        }
        float s = 0.f;
        #pragma unroll
        for (int i = 0; i < C_DIM; ++i) { v[i] = __expf(v[i] - mx); s += v[i]; }
        float inv = 1.f / s;
        #pragma unroll
        for (int i = 0; i < C_DIM; ++i) sA[i * C_DIM + j] = v[i] * inv;
    } else if (tid < 2 * C_DIM) {
        // B: softmax over axis 1 (m), row c
        int c = tid - C_DIM;
        float mx = -1e30f;
        for (int m = 0; m < M_DIM; ++m)
            mx = fmaxf(mx, lB[(c * M_DIM + m) * G_DIM + g]);
        float s = 0.f;
        for (int m = 0; m < M_DIM; ++m) {
            float e = __expf(lB[(c * M_DIM + m) * G_DIM + g] - mx);
            sB[c * M_DIM + m] = e;
            s += e;
        }
        float inv = 1.f / s;
        for (int m = 0; m < M_DIM; ++m) sB[c * M_DIM + m] *= inv;
    } else if (tid == 2 * C_DIM) {
        // Pi: softmax over c
        float v[C_DIM];
        float mx = -1e30f;
        #pragma unroll
        for (int c = 0; c < C_DIM; ++c) {
            v[c] = lPi[c * G_DIM + g];
            mx = fmaxf(mx, v[c]);
        }
        float s = 0.f;
        #pragma unroll
        for (int c = 0; c < C_DIM; ++c) { v[c] = __expf(v[c] - mx); s += v[c]; }
        float inv = 1.f / s;
        #pragma unroll
        for (int c = 0; c < C_DIM; ++c) sPi[c] = v[c] * inv;
    }
    __syncthreads();

    const int base = t * N1;
    float ll = 0.f;

    // ---- fused leaves (level 10) + level 9 (512 parents) ----
    for (int idx = tid; idx < 512; idx += 256) {
        int ppos = 511 + idx;                    // 2^9-1 + idx
        float s[C_DIM];
        #pragma unroll
        for (int j = 0; j < C_DIM; ++j) s[j] = 0.f;
        #pragma unroll
        for (int ch = 0; ch < 2; ++ch) {
            int cpos = 2 * ppos + 1 + ch;        // leaf position
            int xv = x[inv_map[base + cpos]];
            float b[C_DIM]; float nu = 0.f;
            #pragma unroll
            for (int j = 0; j < C_DIM; ++j) {
                b[j] = sPi[j] * sB[j * M_DIM + xv];
                nu += b[j];
            }
            float inv = 0.5f / nu;               // normalize + fold child /2
            #pragma unroll
            for (int j = 0; j < C_DIM; ++j) s[j] += b[j] * inv;
            ll += __logf(nu);
        }
        int xv = x[inv_map[base + ppos]];
        float nu = 0.f;
        float bp[C_DIM];
        #pragma unroll
        for (int i = 0; i < C_DIM; ++i) {
            float ti = 0.f;
            #pragma unroll
            for (int j = 0; j < C_DIM; ++j) ti += sA[i * C_DIM + j] * s[j];
            float v = sB[i * M_DIM + xv] * ti;
            bp[i] = v; nu += v;
        }
        float inv = 1.f / nu;
        ll += __logf(nu);
        #pragma unroll
        for (int i = 0; i < C_DIM; ++i) buf0[i * 512 + idx] = bp[i] * inv;
    }
    __syncthreads();

    // ---- levels 8 .. 0 ----
    float* cur = buf0; int curS = 512;
    float* nxt = buf1;
    for (int l = DEPTH - 2; l >= 0; --l) {
        int cnt = 1 << l;
        for (int idx = tid; idx < cnt; idx += 256) {
            int ppos = cnt - 1 + idx;
            float s[C_DIM];
            #pragma unroll
            for (int j = 0; j < C_DIM; ++j) {
                float2 cv = ((const float2*)(cur + j * curS))[idx];  // children 2idx,2idx+1
                s[j] = 0.5f * (cv.x + cv.y);
            }
            int xv = x[inv_map[base + ppos]];
            float nu = 0.f;
            float bp[C_DIM];
            #pragma unroll
            for (int i = 0; i < C_DIM; ++i) {
                float ti = 0.f;
                #pragma unroll
                for (int j = 0; j < C_DIM; ++j) ti += sA[i * C_DIM + j] * s[j];
                float v = sB[i * M_DIM + xv] * ti;
                bp[i] = v; nu += v;
            }
            float inv = 1.f / nu;
            ll += __logf(nu);
            #pragma unroll
            for (int i = 0; i < C_DIM; ++i) nxt[i * cnt + idx] = bp[i] * inv;
        }
        __syncthreads();
        float* tmp = cur; cur = nxt; nxt = tmp; curS = cnt;
    }

    // ---- block-wide reduction of ll ----
    float v = ll;
    #pragma unroll
    for (int off = 32; off > 0; off >>= 1) v += __shfl_down(v, off, 64);
    if ((tid & 63) == 0) wsum[tid >> 6] = v;
    __syncthreads();
    if (tid == 0) out[t * G_DIM + g] = wsum[0] + wsum[1] + wsum[2] + wsum[3];
}

extern "C" void kernel_launch(void* const* d_in, const int* in_sizes, int n_in,
                              void* d_out, int out_size, void* d_ws, size_t ws_size,
                              hipStream_t stream) {
    const int*   x       = (const int*)d_in[0];
    const int*   inv_map = (const int*)d_in[6];
    const float* lA      = (const float*)d_in[7];
    const float* lB      = (const float*)d_in[8];
    const float* lPi     = (const float*)d_in[9];
    float* out = (float*)d_out;

    htmm_kernel<<<dim3(T_TREES * G_DIM), dim3(256), 0, stream>>>(
        x, inv_map, lA, lB, lPi, out);
}

// Round 2
// 237.797 us; speedup vs baseline: 1.8290x; 1.8290x over previous
//
#include <hip/hip_runtime.h>

// UniformBottomUpHTMM: T=64 trees, depth 10 (N1=2047, heap layout), C=16,
// M=64, G=16. One block per (tree,g). All per-level data in LDS; the tree's
// symbols are staged ONCE (coalesced) into a 2KB uint8 LDS array, so the
// level loops touch no global memory at all. Leaves+L9+L8 fused in registers.

#define C_DIM 16
#define M_DIM 64
#define G_DIM 16
#define T_TREES 64
#define N1 2047

__global__ __launch_bounds__(256, 4) void htmm_kernel(
    const int* __restrict__ x,
    const int* __restrict__ inv_map,
    const float* __restrict__ lA,
    const float* __restrict__ lB,
    const float* __restrict__ lPi,
    float* __restrict__ out)
{
    const int g   = blockIdx.x & (G_DIM - 1);
    const int t   = blockIdx.x >> 4;
    const int tid = threadIdx.x;

    __shared__ float sA[C_DIM * C_DIM];       // sA[i*16+j] = softmax_i A[i,j,g]
    __shared__ float sB[C_DIM * M_DIM];       // sB[c*64+m]
    __shared__ float sPi[C_DIM];
    __shared__ unsigned char xs[N1 + 1];      // symbols for this tree (M=64 < 256)
    __shared__ float buf0[C_DIM * 256];       // level-8 betas (SoA, stride 256)
    __shared__ float buf1[C_DIM * 128];       // ping-pong    (SoA, stride 128)
    __shared__ float wsum[4];

    // ---- stage symbols: coalesced, 8 iterations ----
    const int base = t * N1;
    for (int i = tid; i < N1; i += 256)
        xs[i] = (unsigned char)x[inv_map[base + i]];

    // ---- softmaxes, all 256 threads, width-16 shuffle reductions ----
    {   // A: 16-lane segment per column j
        int j = tid >> 4, i = tid & 15;
        float v = lA[(i * C_DIM + j) * G_DIM + g];
        float mx = v;
        #pragma unroll
        for (int m = 1; m < 16; m <<= 1) mx = fmaxf(mx, __shfl_xor(mx, m, 16));
        float e = __expf(v - mx);
        float s = e;
        #pragma unroll
        for (int m = 1; m < 16; m <<= 1) s += __shfl_xor(s, m, 16);
        sA[i * C_DIM + j] = e / s;
    }
    {   // B: 16-lane segment per row c, 4 symbols per lane
        int c = tid >> 4, l16 = tid & 15;
        float e0 = lB[(c * M_DIM + l16 +  0) * G_DIM + g];
        float e1 = lB[(c * M_DIM + l16 + 16) * G_DIM + g];
        float e2 = lB[(c * M_DIM + l16 + 32) * G_DIM + g];
        float e3 = lB[(c * M_DIM + l16 + 48) * G_DIM + g];
        float mx = fmaxf(fmaxf(e0, e1), fmaxf(e2, e3));
        #pragma unroll
        for (int m = 1; m < 16; m <<= 1) mx = fmaxf(mx, __shfl_xor(mx, m, 16));
        e0 = __expf(e0 - mx); e1 = __expf(e1 - mx);
        e2 = __expf(e2 - mx); e3 = __expf(e3 - mx);
        float s = e0 + e1 + e2 + e3;
        #pragma unroll
        for (int m = 1; m < 16; m <<= 1) s += __shfl_xor(s, m, 16);
        float inv = 1.f / s;
        sB[c * M_DIM + l16 +  0] = e0 * inv;
        sB[c * M_DIM + l16 + 16] = e1 * inv;
        sB[c * M_DIM + l16 + 32] = e2 * inv;
        sB[c * M_DIM + l16 + 48] = e3 * inv;
    }
    if (tid < C_DIM) {  // Pi
        float v = lPi[tid * G_DIM + g];
        float mx = v;
        #pragma unroll
        for (int m = 1; m < 16; m <<= 1) mx = fmaxf(mx, __shfl_xor(mx, m, 16));
        float e = __expf(v - mx);
        float s = e;
        #pragma unroll
        for (int m = 1; m < 16; m <<= 1) s += __shfl_xor(s, m, 16);
        sPi[tid] = e / s;
    }
    __syncthreads();

    float ll = 0.f;

    // ---- fused: leaves (L10) + L9 + L8, one L8 node per thread, registers only
    {
        const int idx = tid;
        const int p8  = 255 + idx;
        float s8[C_DIM];
        #pragma unroll
        for (int k = 0; k < C_DIM; ++k) s8[k] = 0.f;
        #pragma unroll
        for (int c9 = 0; c9 < 2; ++c9) {
            const int p9 = 2 * p8 + 1 + c9;
            float s9[C_DIM];
            #pragma unroll
            for (int k = 0; k < C_DIM; ++k) s9[k] = 0.f;
            #pragma unroll
            for (int cl = 0; cl < 2; ++cl) {
                const int xv = xs[2 * p9 + 1 + cl];
                float b[C_DIM]; float nu = 0.f;
                #pragma unroll
                for (int k = 0; k < C_DIM; ++k) {
                    b[k] = sPi[k] * sB[k * M_DIM + xv];
                    nu += b[k];
                }
                float inv = 0.5f / nu;               // normalize + child avg
                #pragma unroll
                for (int k = 0; k < C_DIM; ++k) s9[k] += b[k] * inv;
                ll += __logf(nu);
            }
            const int xv = xs[p9];
            float bp[C_DIM]; float nu = 0.f;
            #pragma unroll
            for (int i = 0; i < C_DIM; ++i) {
                float ti = 0.f;
                #pragma unroll
                for (int j = 0; j < C_DIM; ++j) ti += sA[i * C_DIM + j] * s9[j];
                bp[i] = ti * sB[i * M_DIM + xv];
                nu += bp[i];
            }
            ll += __logf(nu);
            float inv = 0.5f / nu;
            #pragma unroll
            for (int k = 0; k < C_DIM; ++k) s8[k] += bp[k] * inv;
        }
        const int xv = xs[p8];
        float bp[C_DIM]; float nu = 0.f;
        #pragma unroll
        for (int i = 0; i < C_DIM; ++i) {
            float ti = 0.f;
            #pragma unroll
            for (int j = 0; j < C_DIM; ++j) ti += sA[i * C_DIM + j] * s8[j];
            bp[i] = ti * sB[i * M_DIM + xv];
            nu += bp[i];
        }
        ll += __logf(nu);
        float inv = 1.f / nu;
        #pragma unroll
        for (int k = 0; k < C_DIM; ++k) buf0[k * 256 + idx] = bp[k] * inv;
    }
    __syncthreads();

    // ---- L7: 128 nodes, threads 0-127 (waves 0-1) ----
    if (tid < 128) {
        const int idx = tid;
        float s[C_DIM];
        #pragma unroll
        for (int j = 0; j < C_DIM; ++j) {
            float2 cv = ((const float2*)(buf0 + j * 256))[idx];
            s[j] = 0.5f * (cv.x + cv.y);
        }
        const int xv = xs[127 + idx];
        float bp[C_DIM]; float nu = 0.f;
        #pragma unroll
        for (int i = 0; i < C_DIM; ++i) {
            float ti = 0.f;
            #pragma unroll
            for (int j = 0; j < C_DIM; ++j) ti += sA[i * C_DIM + j] * s[j];
            bp[i] = ti * sB[i * M_DIM + xv];
            nu += bp[i];
        }
        ll += __logf(nu);
        float inv = 1.f / nu;
        #pragma unroll
        for (int i = 0; i < C_DIM; ++i) buf1[i * 128 + idx] = bp[i] * inv;
    }
    __syncthreads();

    // ---- L6..L0 (64..1 nodes): wave 0 only, LDS fences instead of barriers
    if (tid < 64) {
        float* cur = buf1; int cs = 128;
        float* nxt = buf0; int ns = 256;
        for (int cnt = 64; cnt >= 1; cnt >>= 1) {
            if (tid < cnt) {
                const int idx = tid;
                float s[C_DIM];
                #pragma unroll
                for (int j = 0; j < C_DIM; ++j) {
                    float a  = cur[j * cs + 2 * idx];
                    float b2 = cur[j * cs + 2 * idx + 1];
                    s[j] = 0.5f * (a + b2);
                }
                const int xv = xs[cnt - 1 + idx];
                float bp[C_DIM]; float nu = 0.f;
                #pragma unroll
                for (int i = 0; i < C_DIM; ++i) {
                    float ti = 0.f;
                    #pragma unroll
                    for (int j = 0; j < C_DIM; ++j) ti += sA[i * C_DIM + j] * s[j];
                    bp[i] = ti * sB[i * M_DIM + xv];
                    nu += bp[i];
                }
                ll += __logf(nu);
                float inv = 1.f / nu;
                #pragma unroll
                for (int i = 0; i < C_DIM; ++i) nxt[i * ns + idx] = bp[i] * inv;
            }
            // wave-internal producer->consumer: drain LDS, pin compiler order
            asm volatile("s_waitcnt lgkmcnt(0)" ::: "memory");
            __builtin_amdgcn_wave_barrier();
            float* tp = cur; cur = nxt; nxt = tp;
            int ts = cs; cs = ns; ns = ts;
        }
    }

    // ---- reduce ll across block ----
    float v = ll;
    #pragma unroll
    for (int off = 32; off > 0; off >>= 1) v += __shfl_down(v, off, 64);
    if ((tid & 63) == 0) wsum[tid >> 6] = v;
    __syncthreads();
    if (tid == 0) out[t * G_DIM + g] = wsum[0] + wsum[1] + wsum[2] + wsum[3];
}

extern "C" void kernel_launch(void* const* d_in, const int* in_sizes, int n_in,
                              void* d_out, int out_size, void* d_ws, size_t ws_size,
                              hipStream_t stream) {
    const int*   x       = (const int*)d_in[0];
    const int*   inv_map = (const int*)d_in[6];
    const float* lA      = (const float*)d_in[7];
    const float* lB      = (const float*)d_in[8];
    const float* lPi     = (const float*)d_in[9];
    float* out = (float*)d_out;

    htmm_kernel<<<dim3(T_TREES * G_DIM), dim3(256), 0, stream>>>(
        x, inv_map, lA, lB, lPi, out);
}